// Round 1
// baseline (554.668 us; speedup 1.0000x reference)
//
#include <hip/hip_runtime.h>
#include <hip/hip_bf16.h>

#define NNA 50000
#define NNB 50000
#define NE  800000
#define HD  256
#define EMBD 128

typedef __attribute__((ext_vector_type(4))) int            i32x4;
typedef __attribute__((ext_vector_type(4))) float          f32x4;
typedef __attribute__((ext_vector_type(8))) short          bf16x8;
typedef __attribute__((ext_vector_type(4))) unsigned short u16x4;

static __device__ __forceinline__ float bf2f(unsigned short u) {
  union { unsigned int i; float f; } v; v.i = ((unsigned int)u) << 16; return v.f;
}
static __device__ __forceinline__ unsigned short f2bf(float f) {
  __hip_bfloat16 h = __float2bfloat16(f);
  return *reinterpret_cast<unsigned short*>(&h);
}

// ---------------- small prep kernels ----------------

// WcatT[l][t][n][k] (bf16, [2][2][256][512]) : k<256 -> Wl[l,rn,k,n] ; k>=256 ->
// (Wr[l,rn]+Wl[l,rs]+Wr[l,rs])[k-256][n].  t=0:a (rn=1,rs=2)  t=1:b (rn=0,rs=3)
__global__ void k_prep_wcat(const float* __restrict__ Wl, const float* __restrict__ Wr,
                            unsigned short* __restrict__ WcatT) {
  int id = blockIdx.x * 256 + threadIdx.x;
  if (id >= 2 * 2 * 512 * 256) return;
  int n = id & 255;
  int k = (id >> 8) & 511;
  int t = (id >> 17) & 1;
  int l = id >> 18;
  int rn = (t == 0) ? 1 : 0;
  int rs = (t == 0) ? 2 : 3;
  float v;
  if (k < HD) {
    v = Wl[((l * 4 + rn) * HD + k) * HD + n];
  } else {
    int kk = k - HD;
    v = Wr[((l * 4 + rn) * HD + kk) * HD + n]
      + Wl[((l * 4 + rs) * HD + kk) * HD + n]
      + Wr[((l * 4 + rs) * HD + kk) * HD + n];
  }
  WcatT[((l * 2 + t) * HD + n) * 512 + k] = f2bf(v);
}

__global__ void k_prep_bias(const float* __restrict__ bl, float* __restrict__ bias) {
  int id = blockIdx.x * 256 + threadIdx.x;  // [l][t][n]
  if (id >= 2 * 2 * 256) return;
  int n = id & 255; int t = (id >> 8) & 1; int l = id >> 9;
  int rn = (t == 0) ? 1 : 0;
  int rs = (t == 0) ? 2 : 3;
  bias[id] = bl[(l * 4 + rn) * HD + n] + bl[(l * 4 + rs) * HD + n];
}

__global__ void k_prep_lin(const float* __restrict__ linW, unsigned short* __restrict__ linWT) {
  int id = blockIdx.x * 256 + threadIdx.x;  // [n][k] 128x256
  if (id >= EMBD * HD) return;
  int k = id & 255; int n = id >> 8;
  linWT[n * HD + k] = f2bf(linW[k * EMBD + n]);
}

__global__ void k_f32_to_bf16(const float* __restrict__ in, unsigned short* __restrict__ out, int n4) {
  int i = blockIdx.x * blockDim.x + threadIdx.x;
  int stride = gridDim.x * blockDim.x;
  for (; i < n4; i += stride) {
    f32x4 v = reinterpret_cast<const f32x4*>(in)[i];
    u16x4 o;
    o[0] = f2bf(v[0]); o[1] = f2bf(v[1]); o[2] = f2bf(v[2]); o[3] = f2bf(v[3]);
    reinterpret_cast<u16x4*>(out)[i] = o;
  }
}

// ---------------- adjacency bucketing (once per relation) ----------------

__global__ void k_fill_slots(const int* __restrict__ edges, int* __restrict__ cnt,
                             int* __restrict__ slots, int nE) {
  int e = blockIdx.x * 256 + threadIdx.x;
  if (e >= nE) return;
  int src = edges[e];
  int dst = edges[nE + e];
  int pos = atomicAdd(&cnt[dst], 1);
  if (pos < 64) slots[dst * 64 + pos] = src;
}

// ---------------- atomic-free mean aggregation ----------------
// one wave per dst row; 64 lanes x 4 bf16 = 256 features
__global__ void k_aggregate(const unsigned short* __restrict__ xsrc,
                            const int* __restrict__ slots, const int* __restrict__ cnt,
                            unsigned short* __restrict__ mean_out, int ndst) {
  int w = blockIdx.x * 4 + (threadIdx.x >> 6);
  int lane = threadIdx.x & 63;
  if (w >= ndst) return;
  int deg = cnt[w];
  int m = deg < 64 ? deg : 64;
  const int* sl = slots + w * 64;
  float a0 = 0.f, a1 = 0.f, a2 = 0.f, a3 = 0.f;
  float b0 = 0.f, b1 = 0.f, b2 = 0.f, b3 = 0.f;
  int j = 0;
  for (; j + 2 <= m; j += 2) {
    int s0 = sl[j], s1 = sl[j + 1];
    u16x4 u0 = *reinterpret_cast<const u16x4*>(xsrc + s0 * HD + lane * 4);
    u16x4 u1 = *reinterpret_cast<const u16x4*>(xsrc + s1 * HD + lane * 4);
    a0 += bf2f(u0[0]); a1 += bf2f(u0[1]); a2 += bf2f(u0[2]); a3 += bf2f(u0[3]);
    b0 += bf2f(u1[0]); b1 += bf2f(u1[1]); b2 += bf2f(u1[2]); b3 += bf2f(u1[3]);
  }
  if (j < m) {
    int s0 = sl[j];
    u16x4 u0 = *reinterpret_cast<const u16x4*>(xsrc + s0 * HD + lane * 4);
    a0 += bf2f(u0[0]); a1 += bf2f(u0[1]); a2 += bf2f(u0[2]); a3 += bf2f(u0[3]);
  }
  float inv = deg > 0 ? 1.0f / (float)deg : 0.0f;
  u16x4 o;
  o[0] = f2bf((a0 + b0) * inv);
  o[1] = f2bf((a1 + b1) * inv);
  o[2] = f2bf((a2 + b2) * inv);
  o[3] = f2bf((a3 + b3) * inv);
  *reinterpret_cast<u16x4*>(mean_out + w * HD + lane * 4) = o;
}

// ---------------- fused bf16 MFMA GEMM ----------------
// C[M][N] = relu?( [Alo | Ahi](M x Ktot) @ BT^T + bias )
// Alo/Ahi: bf16 row-major [M][256]. BT: bf16 row-major [N][Ktot] (i.e. W^T).
// BM=BN=128, BK=64, 256 threads = 4 waves (2x2), 64x64 per wave.
template <bool RELU, bool OUTF32>
__global__ __launch_bounds__(256)
void k_gemm(const unsigned short* __restrict__ Alo,
            const unsigned short* __restrict__ Ahi,
            const unsigned short* __restrict__ BT,
            const float* __restrict__ bias,
            void* __restrict__ Cout,
            int M, int N, int Ktot, int Klo) {
  __shared__ char smem[32768];  // A tile 16KB | B tile 16KB
  const int t = threadIdx.x;
  const int bm = blockIdx.x, bn = blockIdx.y;
  const int lane = t & 63, wid = t >> 6;
  const int wm = wid >> 1, wn = wid & 1;
  const int l15 = lane & 15, l4 = lane >> 4;
  const int rowA0 = t >> 3;   // 0..31, +32 per pass
  const int seg = t & 7;      // 16B segment within 128B row

  f32x4 acc[4][4];
#pragma unroll
  for (int i = 0; i < 4; ++i)
#pragma unroll
    for (int j = 0; j < 4; ++j) acc[i][j] = (f32x4){0.f, 0.f, 0.f, 0.f};

  const int nks = Ktot >> 6;
  for (int ks = 0; ks < nks; ++ks) {
    const int kglob = ks << 6;
    const unsigned short* Asrc = (kglob < Klo) ? Alo : Ahi;
    const int kbase = (kglob < Klo) ? kglob : (kglob - Klo);
    i32x4 ra[4], rb[4];
#pragma unroll
    for (int p = 0; p < 4; ++p) {
      int row = rowA0 + p * 32;
      int rg = bm * 128 + row;
      if (rg < M)
        ra[p] = *reinterpret_cast<const i32x4*>(Asrc + rg * HD + kbase + seg * 8);
      else
        ra[p] = (i32x4){0, 0, 0, 0};
      int ng = bn * 128 + row;
      rb[p] = *reinterpret_cast<const i32x4*>(BT + ng * Ktot + kglob + seg * 8);
    }
    __syncthreads();
#pragma unroll
    for (int p = 0; p < 4; ++p) {
      int row = rowA0 + p * 32;
      int off = row * 128 + ((seg * 16) ^ ((row & 7) << 4));
      *reinterpret_cast<i32x4*>(smem + off) = ra[p];
      *reinterpret_cast<i32x4*>(smem + 16384 + off) = rb[p];
    }
    __syncthreads();
#pragma unroll
    for (int kk = 0; kk < 2; ++kk) {
      bf16x8 af[4], bfr[4];
#pragma unroll
      for (int f = 0; f < 4; ++f) {
        int r = wm * 64 + f * 16 + l15;
        af[f] = *reinterpret_cast<const bf16x8*>(
            smem + r * 128 + ((kk * 64 + l4 * 16) ^ ((r & 7) << 4)));
        int n = wn * 64 + f * 16 + l15;
        bfr[f] = *reinterpret_cast<const bf16x8*>(
            smem + 16384 + n * 128 + ((kk * 64 + l4 * 16) ^ ((n & 7) << 4)));
      }
#pragma unroll
      for (int fm = 0; fm < 4; ++fm)
#pragma unroll
        for (int fn = 0; fn < 4; ++fn)
          acc[fm][fn] = __builtin_amdgcn_mfma_f32_16x16x32_bf16(af[fm], bfr[fn], acc[fm][fn], 0, 0, 0);
    }
  }

#pragma unroll
  for (int fm = 0; fm < 4; ++fm) {
    int row0 = bm * 128 + wm * 64 + fm * 16 + l4 * 4;
#pragma unroll
    for (int fn = 0; fn < 4; ++fn) {
      int col = bn * 128 + wn * 64 + fn * 16 + l15;
      float bv = bias[col];
      f32x4 d = acc[fm][fn];
#pragma unroll
      for (int r = 0; r < 4; ++r) {
        int rg = row0 + r;
        if (rg < M) {
          float v = d[r] + bv;
          if (RELU) v = v > 0.f ? v : 0.f;
          if (OUTF32)
            reinterpret_cast<float*>(Cout)[rg * N + col] = v;
          else
            reinterpret_cast<unsigned short*>(Cout)[rg * N + col] = f2bf(v);
        }
      }
    }
  }
}

// ---------------- launch ----------------

extern "C" void kernel_launch(void* const* d_in, const int* in_sizes, int n_in,
                              void* d_out, int out_size, void* d_ws, size_t ws_size,
                              hipStream_t stream) {
  const float* x_a  = (const float*)d_in[0];
  const float* x_b  = (const float*)d_in[1];
  const int*   e_ab = (const int*)d_in[2];
  const int*   e_ba = (const int*)d_in[3];
  const float* Wl   = (const float*)d_in[4];
  const float* bl   = (const float*)d_in[5];
  const float* Wr   = (const float*)d_in[6];
  const float* linW = (const float*)d_in[7];
  const float* linb = (const float*)d_in[8];
  float* out = (float*)d_out;

  char* ws = (char*)d_ws;
  size_t off = 0;
  auto alloc = [&](size_t bytes) {
    char* p = ws + off;
    off += (bytes + 255) & ~(size_t)255;
    return p;
  };
  unsigned short* xa0    = (unsigned short*)alloc((size_t)NNA * HD * 2);
  unsigned short* xb0    = (unsigned short*)alloc((size_t)NNB * HD * 2);
  unsigned short* xa1    = (unsigned short*)alloc((size_t)NNA * HD * 2);
  unsigned short* xb1    = (unsigned short*)alloc((size_t)NNB * HD * 2);
  unsigned short* mean_a = (unsigned short*)alloc((size_t)NNA * HD * 2);
  unsigned short* mean_b = (unsigned short*)alloc((size_t)NNB * HD * 2);
  int* slots_a = (int*)alloc((size_t)NNA * 64 * 4);
  int* slots_b = (int*)alloc((size_t)NNB * 64 * 4);
  int* cnt_a   = (int*)alloc((size_t)NNA * 4);
  int* cnt_b   = (int*)alloc((size_t)NNB * 4);
  unsigned short* wcatT  = (unsigned short*)alloc((size_t)2 * 2 * 256 * 512 * 2);
  float*          biasv  = (float*)alloc((size_t)2 * 2 * 256 * 4);
  unsigned short* linWT  = (unsigned short*)alloc((size_t)EMBD * HD * 2);
  (void)ws_size; (void)in_sizes; (void)n_in; (void)out_size;

  hipMemsetAsync(cnt_a, 0, (size_t)NNA * 4, stream);
  hipMemsetAsync(cnt_b, 0, (size_t)NNB * 4, stream);

  k_prep_wcat<<<2048, 256, 0, stream>>>(Wl, Wr, wcatT);
  k_prep_bias<<<4, 256, 0, stream>>>(bl, biasv);
  k_prep_lin<<<128, 256, 0, stream>>>(linW, linWT);

  k_f32_to_bf16<<<2048, 256, 0, stream>>>(x_a, xa0, NNA * HD / 4);
  k_f32_to_bf16<<<2048, 256, 0, stream>>>(x_b, xb0, NNB * HD / 4);

  k_fill_slots<<<(NE + 255) / 256, 256, 0, stream>>>(e_ba, cnt_a, slots_a, NE);
  k_fill_slots<<<(NE + 255) / 256, 256, 0, stream>>>(e_ab, cnt_b, slots_b, NE);

  unsigned short* xa_cur = xa0; unsigned short* xb_cur = xb0;
  unsigned short* xa_nxt = xa1; unsigned short* xb_nxt = xb1;

  for (int l = 0; l < 2; ++l) {
    k_aggregate<<<NNA / 4, 256, 0, stream>>>(xb_cur, slots_a, cnt_a, mean_a, NNA);
    k_aggregate<<<NNB / 4, 256, 0, stream>>>(xa_cur, slots_b, cnt_b, mean_b, NNB);
    dim3 g((NNA + 127) / 128, 2);
    k_gemm<true, false><<<g, 256, 0, stream>>>(
        mean_a, xa_cur, wcatT + (size_t)(l * 2 + 0) * 256 * 512,
        biasv + (l * 2 + 0) * 256, xa_nxt, NNA, 256, 512, 256);
    k_gemm<true, false><<<g, 256, 0, stream>>>(
        mean_b, xb_cur, wcatT + (size_t)(l * 2 + 1) * 256 * 512,
        biasv + (l * 2 + 1) * 256, xb_nxt, NNB, 256, 512, 256);
    unsigned short* ta = xa_cur; xa_cur = xa_nxt; xa_nxt = ta;
    unsigned short* tb = xb_cur; xb_cur = xb_nxt; xb_nxt = tb;
  }

  dim3 gf((NNA + 127) / 128, 1);
  k_gemm<false, true><<<gf, 256, 0, stream>>>(
      xa_cur, xa_cur, linWT, linb, out, NNA, EMBD, 256, 256);
  k_gemm<false, true><<<gf, 256, 0, stream>>>(
      xb_cur, xb_cur, linWT, linb, out + (size_t)NNA * EMBD, NNB, EMBD, 256, 256);
}

// Round 3
// 503.742 us; speedup vs baseline: 1.1011x; 1.1011x over previous
//
#include <hip/hip_runtime.h>
#include <hip/hip_bf16.h>

#define NNA 50000
#define NNB 50000
#define NE  800000
#define HD  256
#define EMBD 128

typedef __attribute__((ext_vector_type(4))) int            i32x4;
typedef __attribute__((ext_vector_type(4))) float          f32x4;
typedef __attribute__((ext_vector_type(8))) short          bf16x8;
typedef __attribute__((ext_vector_type(4))) unsigned short u16x4;
typedef __attribute__((ext_vector_type(8))) unsigned short u16x8;

static __device__ __forceinline__ float bf2f(unsigned short u) {
  union { unsigned int i; float f; } v; v.i = ((unsigned int)u) << 16; return v.f;
}
static __device__ __forceinline__ unsigned short f2bf(float f) {
  __hip_bfloat16 h = __float2bfloat16(f);
  return *reinterpret_cast<unsigned short*>(&h);
}

// ---------------- small prep kernels ----------------

// WcatT[l][t][n][k] (bf16, [2][2][256][512]) : k<256 -> Wl[l,rn,k,n] ; k>=256 ->
// (Wr[l,rn]+Wl[l,rs]+Wr[l,rs])[k-256][n].  t=0:a (rn=1,rs=2)  t=1:b (rn=0,rs=3)
__global__ void k_prep_wcat(const float* __restrict__ Wl, const float* __restrict__ Wr,
                            unsigned short* __restrict__ WcatT) {
  int id = blockIdx.x * 256 + threadIdx.x;
  if (id >= 2 * 2 * 512 * 256) return;
  int n = id & 255;
  int k = (id >> 8) & 511;
  int t = (id >> 17) & 1;
  int l = id >> 18;
  int rn = (t == 0) ? 1 : 0;
  int rs = (t == 0) ? 2 : 3;
  float v;
  if (k < HD) {
    v = Wl[((l * 4 + rn) * HD + k) * HD + n];
  } else {
    int kk = k - HD;
    v = Wr[((l * 4 + rn) * HD + kk) * HD + n]
      + Wl[((l * 4 + rs) * HD + kk) * HD + n]
      + Wr[((l * 4 + rs) * HD + kk) * HD + n];
  }
  WcatT[((l * 2 + t) * HD + n) * 512 + k] = f2bf(v);
}

__global__ void k_prep_bias(const float* __restrict__ bl, float* __restrict__ bias) {
  int id = blockIdx.x * 256 + threadIdx.x;  // [l][t][n]
  if (id >= 2 * 2 * 256) return;
  int n = id & 255; int t = (id >> 8) & 1; int l = id >> 9;
  int rn = (t == 0) ? 1 : 0;
  int rs = (t == 0) ? 2 : 3;
  bias[id] = bl[(l * 4 + rn) * HD + n] + bl[(l * 4 + rs) * HD + n];
}

__global__ void k_prep_lin(const float* __restrict__ linW, unsigned short* __restrict__ linWT) {
  int id = blockIdx.x * 256 + threadIdx.x;  // [n][k] 128x256
  if (id >= EMBD * HD) return;
  int k = id & 255; int n = id >> 8;
  linWT[n * HD + k] = f2bf(linW[k * EMBD + n]);
}

__global__ void k_f32_to_bf16(const float* __restrict__ in, unsigned short* __restrict__ out, int n4) {
  int i = blockIdx.x * blockDim.x + threadIdx.x;
  int stride = gridDim.x * blockDim.x;
  for (; i < n4; i += stride) {
    f32x4 v = reinterpret_cast<const f32x4*>(in)[i];
    u16x4 o;
    o[0] = f2bf(v[0]); o[1] = f2bf(v[1]); o[2] = f2bf(v[2]); o[3] = f2bf(v[3]);
    reinterpret_cast<u16x4*>(out)[i] = o;
  }
}

// ---------------- adjacency bucketing (once per relation) ----------------

__global__ void k_fill_slots(const int* __restrict__ edges, int* __restrict__ cnt,
                             int* __restrict__ slots, int nE) {
  int e = blockIdx.x * 256 + threadIdx.x;
  if (e >= nE) return;
  int src = edges[e];
  int dst = edges[nE + e];
  int pos = atomicAdd(&cnt[dst], 1);
  if (pos < 64) slots[dst * 64 + pos] = src;
}

// ---------------- atomic-free mean aggregation (both types fused) ----------------
// one wave per dst row; 16B/lane, 2 rows per load instruction, 8 rows in flight
__global__ __launch_bounds__(256)
void k_aggregate(const unsigned short* __restrict__ xa,   // gathered for type-b dsts
                 const unsigned short* __restrict__ xb,   // gathered for type-a dsts
                 const int* __restrict__ slots_a, const int* __restrict__ cnt_a,
                 const int* __restrict__ slots_b, const int* __restrict__ cnt_b,
                 unsigned short* __restrict__ mean_a, unsigned short* __restrict__ mean_b) {
  int w = blockIdx.x * 4 + (threadIdx.x >> 6);
  int lane = threadIdx.x & 63;
  const unsigned short* xsrc;
  const int* sl;
  int deg;
  unsigned short* outp;
  if (w < NNA) {
    xsrc = xb; sl = slots_a + (size_t)w * 64; deg = cnt_a[w];
    outp = mean_a + (size_t)w * HD;
  } else {
    int v = w - NNA;
    xsrc = xa; sl = slots_b + (size_t)v * 64; deg = cnt_b[v];
    outp = mean_b + (size_t)v * HD;
  }
  int m = deg < 64 ? deg : 64;
  int s_all = sl[lane];              // one coalesced 256B slot read per wave
  const int half = lane >> 5;
  const int l31 = lane & 31;

  float acc[8];
#pragma unroll
  for (int k = 0; k < 8; ++k) acc[k] = 0.f;

  int j = 0;
  for (; j + 8 <= m; j += 8) {
    int sj[4];
#pragma unroll
    for (int i = 0; i < 4; ++i) sj[i] = __shfl(s_all, j + 2 * i + half);
    u16x8 v[4];
#pragma unroll
    for (int i = 0; i < 4; ++i)
      v[i] = *reinterpret_cast<const u16x8*>(xsrc + (size_t)sj[i] * HD + l31 * 8);
#pragma unroll
    for (int i = 0; i < 4; ++i)
#pragma unroll
      for (int k = 0; k < 8; ++k) acc[k] += bf2f(v[i][k]);
  }
  for (; j + 2 <= m; j += 2) {
    int sj = __shfl(s_all, j + half);
    u16x8 v = *reinterpret_cast<const u16x8*>(xsrc + (size_t)sj * HD + l31 * 8);
#pragma unroll
    for (int k = 0; k < 8; ++k) acc[k] += bf2f(v[k]);
  }
  if (j < m && half == 0) {
    int sj = __shfl(s_all, j);
    u16x8 v = *reinterpret_cast<const u16x8*>(xsrc + (size_t)sj * HD + l31 * 8);
#pragma unroll
    for (int k = 0; k < 8; ++k) acc[k] += bf2f(v[k]);
  }

  // combine the two half-wave partial sums (feature f = l31*8+k)
#pragma unroll
  for (int k = 0; k < 8; ++k) acc[k] += __shfl_xor(acc[k], 32);

  float inv = deg > 0 ? 1.0f / (float)deg : 0.0f;
  if (half == 0) {
    u16x8 o;
#pragma unroll
    for (int k = 0; k < 8; ++k) o[k] = f2bf(acc[k] * inv);
    *reinterpret_cast<u16x8*>(outp + l31 * 8) = o;
  }
}

// ---------------- fused bf16 MFMA GEMM ----------------
// C[M][N] = relu?( [Alo | Ahi](M x Ktot) @ BT^T + bias )
// Alo/Ahi: bf16 row-major [M][256]. BT: bf16 row-major [N][Ktot] (i.e. W^T).
// BM=BN=128, BK=64, 256 threads = 4 waves (2x2), 64x64 per wave.
// blockIdx.z selects the problem instance via strides.
template <bool RELU, bool OUTF32>
__global__ __launch_bounds__(256)
void k_gemm(const unsigned short* __restrict__ Alo,
            const unsigned short* __restrict__ Ahi,
            const unsigned short* __restrict__ BT,
            const float* __restrict__ bias,
            void* __restrict__ Cout,
            int M, int N, int Ktot, int Klo,
            long long sA, long long sB, long long sBias, long long sCbytes) {
  const int z = blockIdx.z;
  Alo += (long long)z * sA;
  Ahi += (long long)z * sA;
  BT += (long long)z * sB;
  bias += (long long)z * sBias;
  Cout = (void*)((char*)Cout + (long long)z * sCbytes);

  __shared__ char smem[32768];  // A tile 16KB | B tile 16KB
  const int t = threadIdx.x;
  const int bm = blockIdx.x, bn = blockIdx.y;
  const int lane = t & 63, wid = t >> 6;
  const int wm = wid >> 1, wn = wid & 1;
  const int l15 = lane & 15, l4 = lane >> 4;
  const int rowA0 = t >> 3;   // 0..31, +32 per pass
  const int seg = t & 7;      // 16B segment within 128B row

  f32x4 acc[4][4];
#pragma unroll
  for (int i = 0; i < 4; ++i)
#pragma unroll
    for (int j = 0; j < 4; ++j) acc[i][j] = (f32x4){0.f, 0.f, 0.f, 0.f};

  const int nks = Ktot >> 6;
  for (int ks = 0; ks < nks; ++ks) {
    const int kglob = ks << 6;
    const unsigned short* Asrc = (kglob < Klo) ? Alo : Ahi;
    const int kbase = (kglob < Klo) ? kglob : (kglob - Klo);
    i32x4 ra[4], rb[4];
#pragma unroll
    for (int p = 0; p < 4; ++p) {
      int row = rowA0 + p * 32;
      int rg = bm * 128 + row;
      if (rg < M)
        ra[p] = *reinterpret_cast<const i32x4*>(Asrc + (size_t)rg * HD + kbase + seg * 8);
      else
        ra[p] = (i32x4){0, 0, 0, 0};
      int ng = bn * 128 + row;
      rb[p] = *reinterpret_cast<const i32x4*>(BT + (size_t)ng * Ktot + kglob + seg * 8);
    }
    __syncthreads();
#pragma unroll
    for (int p = 0; p < 4; ++p) {
      int row = rowA0 + p * 32;
      int off = row * 128 + ((seg * 16) ^ ((row & 7) << 4));
      *reinterpret_cast<i32x4*>(smem + off) = ra[p];
      *reinterpret_cast<i32x4*>(smem + 16384 + off) = rb[p];
    }
    __syncthreads();
#pragma unroll
    for (int kk = 0; kk < 2; ++kk) {
      bf16x8 af[4], bfr[4];
#pragma unroll
      for (int f = 0; f < 4; ++f) {
        int r = wm * 64 + f * 16 + l15;
        af[f] = *reinterpret_cast<const bf16x8*>(
            smem + r * 128 + ((kk * 64 + l4 * 16) ^ ((r & 7) << 4)));
        int n = wn * 64 + f * 16 + l15;
        bfr[f] = *reinterpret_cast<const bf16x8*>(
            smem + 16384 + n * 128 + ((kk * 64 + l4 * 16) ^ ((n & 7) << 4)));
      }
#pragma unroll
      for (int fm = 0; fm < 4; ++fm)
#pragma unroll
        for (int fn = 0; fn < 4; ++fn)
          acc[fm][fn] = __builtin_amdgcn_mfma_f32_16x16x32_bf16(af[fm], bfr[fn], acc[fm][fn], 0, 0, 0);
    }
  }

#pragma unroll
  for (int fm = 0; fm < 4; ++fm) {
    int row0 = bm * 128 + wm * 64 + fm * 16 + l4 * 4;
#pragma unroll
    for (int fn = 0; fn < 4; ++fn) {
      int col = bn * 128 + wn * 64 + fn * 16 + l15;
      float bv = bias[col];
      f32x4 d = acc[fm][fn];
#pragma unroll
      for (int r = 0; r < 4; ++r) {
        int rg = row0 + r;
        if (rg < M) {
          float v = d[r] + bv;
          if (RELU) v = v > 0.f ? v : 0.f;
          if (OUTF32)
            reinterpret_cast<float*>(Cout)[(size_t)rg * N + col] = v;
          else
            reinterpret_cast<unsigned short*>(Cout)[(size_t)rg * N + col] = f2bf(v);
        }
      }
    }
  }
}

// ---------------- launch ----------------

extern "C" void kernel_launch(void* const* d_in, const int* in_sizes, int n_in,
                              void* d_out, int out_size, void* d_ws, size_t ws_size,
                              hipStream_t stream) {
  const float* x_a  = (const float*)d_in[0];
  const float* x_b  = (const float*)d_in[1];
  const int*   e_ab = (const int*)d_in[2];
  const int*   e_ba = (const int*)d_in[3];
  const float* Wl   = (const float*)d_in[4];
  const float* bl   = (const float*)d_in[5];
  const float* Wr   = (const float*)d_in[6];
  const float* linW = (const float*)d_in[7];
  const float* linb = (const float*)d_in[8];
  float* out = (float*)d_out;

  char* ws = (char*)d_ws;
  size_t off = 0;
  auto alloc = [&](size_t bytes) {
    char* p = ws + off;
    off += (bytes + 255) & ~(size_t)255;
    return p;
  };
  // x buffers hold [a | b] contiguously so GEMM/aggregate can stride by z
  unsigned short* x0   = (unsigned short*)alloc((size_t)2 * NNA * HD * 2);
  unsigned short* x1   = (unsigned short*)alloc((size_t)2 * NNA * HD * 2);
  unsigned short* mean = (unsigned short*)alloc((size_t)2 * NNA * HD * 2);
  int* slots_a = (int*)alloc((size_t)NNA * 64 * 4);
  int* slots_b = (int*)alloc((size_t)NNB * 64 * 4);
  int* cnt_a   = (int*)alloc((size_t)NNA * 4);
  int* cnt_b   = (int*)alloc((size_t)NNB * 4);
  unsigned short* wcatT  = (unsigned short*)alloc((size_t)2 * 2 * 256 * 512 * 2);
  float*          biasv  = (float*)alloc((size_t)2 * 2 * 256 * 4);
  unsigned short* linWT  = (unsigned short*)alloc((size_t)EMBD * HD * 2);
  (void)ws_size; (void)in_sizes; (void)n_in; (void)out_size;

  hipMemsetAsync(cnt_a, 0, (size_t)NNA * 4, stream);
  hipMemsetAsync(cnt_b, 0, (size_t)NNB * 4, stream);

  k_prep_wcat<<<2048, 256, 0, stream>>>(Wl, Wr, wcatT);
  k_prep_bias<<<4, 256, 0, stream>>>(bl, biasv);
  k_prep_lin<<<128, 256, 0, stream>>>(linW, linWT);

  k_f32_to_bf16<<<2048, 256, 0, stream>>>(x_a, x0, NNA * HD / 4);
  k_f32_to_bf16<<<2048, 256, 0, stream>>>(x_b, x0 + (size_t)NNA * HD, NNB * HD / 4);

  k_fill_slots<<<(NE + 255) / 256, 256, 0, stream>>>(e_ba, cnt_a, slots_a, NE);
  k_fill_slots<<<(NE + 255) / 256, 256, 0, stream>>>(e_ab, cnt_b, slots_b, NE);

  unsigned short* xcur = x0;
  unsigned short* xnxt = x1;

  for (int l = 0; l < 2; ++l) {
    k_aggregate<<<(NNA + NNB) / 4, 256, 0, stream>>>(
        xcur, xcur + (size_t)NNA * HD, slots_a, cnt_a, slots_b, cnt_b,
        mean, mean + (size_t)NNA * HD);
    dim3 g((NNA + 127) / 128, 2, 2);
    k_gemm<true, false><<<g, 256, 0, stream>>>(
        mean, xcur, wcatT + (size_t)l * 2 * 256 * 512, biasv + l * 2 * 256, xnxt,
        NNA, 256, 512, 256,
        (long long)NNA * HD, 256 * 512, 256, (long long)NNA * HD * 2);
    unsigned short* tmp = xcur; xcur = xnxt; xnxt = tmp;
  }

  dim3 gf((NNA + 127) / 128, 1, 2);
  k_gemm<false, true><<<gf, 256, 0, stream>>>(
      xcur, xcur, linWT, linb, out,
      NNA, EMBD, 256, 256,
      (long long)NNA * HD, 0, 0, (long long)NNA * EMBD * 4);
}